// Round 7
// baseline (104383.813 us; speedup 1.0000x reference)
//
#include <hip/hip_runtime.h>
#include <math.h>

#define Tn   16384
#define Mg   200
#define Nc   6
#define TOT  1200
#define Kk   25
#define Din  784
#define CH   32                 // Za/Y chunk length (steps)

// ---------------------------------------------------------------- transpose
__global__ void transpose_k(const float* __restrict__ src, float* __restrict__ dst,
                            int R, int C) {
    __shared__ float tile[32][33];
    int bx = blockIdx.x * 32, by = blockIdx.y * 32;
    int x = bx + threadIdx.x;
    for (int j = 0; j < 32; j += 8) {
        int y = by + threadIdx.y + j;
        if (x < C && y < R) tile[threadIdx.y + j][threadIdx.x] = src[(size_t)y * C + x];
    }
    __syncthreads();
    int x2 = by + threadIdx.x;
    for (int j = 0; j < 32; j += 8) {
        int y2 = bx + threadIdx.y + j;
        if (x2 < R && y2 < C) dst[(size_t)y2 * R + x2] = tile[threadIdx.x][threadIdx.y + j];
    }
}

// ------------------------------------------------- Za = X @ Wa^T + ba  (16384 x 200)
__global__ void za_k(const float* __restrict__ X, const float* __restrict__ Wa,
                     const float* __restrict__ ba, float* __restrict__ Za) {
    __shared__ float xs[16][788];
    const int tid = threadIdx.x;
    const int t0  = blockIdx.x * 16;
    for (int idx = tid; idx < 16 * Din; idx += 256) {
        int tt = idx / Din, kk = idx - tt * Din;
        xs[tt][kk] = X[(size_t)(t0 + tt) * Din + kk];
    }
    __syncthreads();
    const int tq = tid & 15, gq = tid >> 4;
    const float4* xrow = reinterpret_cast<const float4*>(&xs[tq][0]);
    for (int g = gq; g < Mg; g += 16) {
        float acc = ba[g];
        const float4* wrow = reinterpret_cast<const float4*>(Wa + (size_t)g * Din);
        for (int k4 = 0; k4 < Din / 4; ++k4) {
            float4 a = xrow[k4], b = wrow[k4];
            acc = fmaf(a.x, b.x, acc); acc = fmaf(a.y, b.y, acc);
            acc = fmaf(a.z, b.z, acc); acc = fmaf(a.w, b.w, acc);
        }
        Za[(size_t)(t0 + tq) * Mg + g] = acc;
    }
}

// ------------------------------------------------------------- serial recurrence
// SINGLE WAVE (64 lanes), zero barriers. Lanes 0-49 own 4 groups (24 cells) each;
// u/psi/bb in registers. Top-25 via ballot quickselect (exact: keys unique).
// Cross-lane: shfl/ballot; LDS only for za chunks, Y ring, 25-slot broadcast
// (wave-synchronous DS ordering, no s_barrier needed).
__launch_bounds__(64, 1)
__global__ void serial_k(const float* __restrict__ Za, const float* __restrict__ WbT,
                         const float* __restrict__ bb,
                         unsigned long long* __restrict__ YP,
                         float* __restrict__ outTail) {
    __shared__ alignas(16) float zs[CH * Mg];                 // 25.6 KB
    __shared__ alignas(16) unsigned long long ypk[CH * Kk];   // 6.4 KB
    __shared__ alignas(16) unsigned long long selL[26];

    const int lane = threadIdx.x;
    const bool grp = (lane < 50);
    const int cell0 = 24 * lane;                // cells [cell0, cell0+24)

    float u[24], ps[24], cb[24];
    #pragma unroll
    for (int i = 0; i < 24; ++i) { u[i] = 0.f; ps[i] = 0.f; cb[i] = 0.f; }
    if (grp) {
        #pragma unroll
        for (int i = 0; i < 6; ++i) {
            float4 v = *reinterpret_cast<const float4*>(bb + cell0 + 4 * i);
            cb[4*i] = v.x; cb[4*i+1] = v.y; cb[4*i+2] = v.z; cb[4*i+3] = v.w;
        }
    }
    if (lane == 0) selL[25] = 0ull;
    float alpha = 0.f;

    // stage chunk 0 of Za (1600 float4)
    #pragma unroll
    for (int j = 0; j < 25; ++j) {
        int f = lane + j * 64;
        *reinterpret_cast<float4*>(zs + 4 * f) =
            *reinterpret_cast<const float4*>(Za + 4 * f);
    }

    const unsigned long long lt = (1ull << lane) - 1ull;

    for (int t = 0; t < Tn; ++t) {
        const int tc = t & (CH - 1);

        float4 za4 = make_float4(0.f, 0.f, 0.f, 0.f);
        if (grp) za4 = *reinterpret_cast<const float4*>(zs + tc * Mg + 4 * lane);

        const float A0  = (alpha == 0.f) ? 1.f : alpha;
        const float inv = 1.f / A0;

        // ---- sigma + local min
        float sg[24];
        float lm = INFINITY;
        if (grp) {
            #pragma unroll
            for (int c = 0; c < 4; ++c) {
                float zc = (c == 0) ? za4.x : (c == 1) ? za4.y : (c == 2) ? za4.z : za4.w;
                #pragma unroll
                for (int j = 0; j < 6; ++j) {
                    int i = 6 * c + j;
                    sg[i] = fmaf(u[i], inv, cb[i] + zc);
                    lm = fminf(lm, sg[i]);
                }
            }
        }
        // wave min (in-register butterfly)
        #pragma unroll
        for (int o = 1; o < 64; o <<= 1) lm = fminf(lm, __shfl_xor(lm, o));
        const float m1 = 1.f - lm;

        // ---- per-group argmax of pi, sortable keys
        float bs[4], bp[4]; int bj[4]; unsigned long long kb[4];
        #pragma unroll
        for (int c = 0; c < 4; ++c) { bs[c] = 0.f; bp[c] = 0.f; bj[c] = 0; kb[c] = 0ull; }
        if (grp) {
            #pragma unroll
            for (int c = 0; c < 4; ++c) {
                float best = -INFINITY, sbv = 0.f, pbv = 0.f; int jb = 0;
                #pragma unroll
                for (int j = 0; j < 6; ++j) {
                    int i = 6 * c + j;
                    float pv = (1.f - ps[i]) * (sg[i] + m1);
                    bool bet = pv > best;                 // strict: first-max kept
                    best = bet ? pv : best;
                    jb  = bet ? j : jb;
                    sbv = bet ? sg[i] : sbv;
                    pbv = bet ? ps[i] : pbv;
                }
                unsigned ub = __float_as_uint(best);
                ub ^= (unsigned)(((int)ub) >> 31) | 0x80000000u;
                int g = 4 * lane + c;
                kb[c] = ((unsigned long long)ub << 32) |
                        (unsigned long long)(0xFFFFFFFFu - (unsigned)g);
                bs[c] = sbv; bp[c] = pbv; bj[c] = jb;
            }
        }

        // ---- quickselect: theta = 25th largest of 200 unique keys (exact)
        unsigned long long A = 0ull, B = ~0ull;
        unsigned long long p = __shfl(kb[0], 0);
        unsigned long long theta;
        while (true) {
            int cnt = __popcll(__ballot(kb[0] >= p)) + __popcll(__ballot(kb[1] >= p))
                    + __popcll(__ballot(kb[2] >= p)) + __popcll(__ballot(kb[3] >= p));
            if (cnt == Kk) { theta = p; break; }
            if (cnt > Kk) A = p; else B = p;
            unsigned long long m0 = __ballot(kb[0] > A && kb[0] < B);
            unsigned long long m1b = __ballot(kb[1] > A && kb[1] < B);
            unsigned long long m2 = __ballot(kb[2] > A && kb[2] < B);
            unsigned long long m3 = __ballot(kb[3] > A && kb[3] < B);
            int cls; unsigned long long mm;
            if (m0)       { cls = 0; mm = m0; }
            else if (m1b) { cls = 1; mm = m1b; }
            else if (m2)  { cls = 2; mm = m2; }
            else          { cls = 3; mm = m3; }
            int sl = __ffsll(mm) - 1;
            unsigned long long kc = (cls == 0) ? kb[0] : (cls == 1) ? kb[1]
                                  : (cls == 2) ? kb[2] : kb[3];
            p = __shfl(kc, sl);
        }

        // ---- selection masks, deterministic slots (class-major, then lane)
        unsigned long long M0 = __ballot(kb[0] >= theta);
        unsigned long long M1 = __ballot(kb[1] >= theta);
        unsigned long long M2 = __ballot(kb[2] >= theta);
        unsigned long long M3 = __ballot(kb[3] >= theta);
        int base0 = 0;
        int base1 = __popcll(M0);
        int base2 = base1 + __popcll(M1);
        int base3 = base2 + __popcll(M2);

        #pragma unroll
        for (int c = 0; c < 4; ++c) {
            unsigned long long Mc = (c == 0) ? M0 : (c == 1) ? M1 : (c == 2) ? M2 : M3;
            int bsee = (c == 0) ? base0 : (c == 1) ? base1 : (c == 2) ? base2 : base3;
            bool s = grp && (kb[c] >= theta);
            float d = 0.f;
            if (s) {
                int slot = bsee + __popcll(Mc & lt);
                float x = fminf(fmaxf(bs[c], -9.f), 9.f);
                float e = __expf(2.f * x);
                float y = (e - 1.f) * __builtin_amdgcn_rcpf(e + 1.f);
                float yv = fmaxf(y, 0.f);
                d = fmaxf(y - 0.5f * bp[c], 0.f);
                int g = 4 * lane + c;
                ypk[tc * Kk + slot] = ((unsigned long long)(unsigned)g << 32) |
                                      (unsigned long long)__float_as_uint(yv);
                int eix = 6 * g + bj[c];
                selL[slot] = ((unsigned long long)(unsigned)eix << 32) |
                             (unsigned long long)__float_as_uint(d);
            }
            // psi decay + one-hot delta for this class
            #pragma unroll
            for (int j = 0; j < 6; ++j) {
                int i = 6 * c + j;
                float add = (j == bj[c]) ? d : 0.f;
                ps[i] = fmaf(ps[i], 0.5f, add);
            }
        }

        // ---- broadcast sel (wave-synchronous LDS read), alpha
        ulonglong2 sr[13];
        #pragma unroll
        for (int q = 0; q < 13; ++q)
            sr[q] = reinterpret_cast<const ulonglong2*>(selL)[q];
        float sd[Kk]; int se[Kk];
        #pragma unroll
        for (int k = 0; k < Kk; ++k) {
            unsigned long long v = (k & 1) ? sr[k >> 1].y : sr[k >> 1].x;
            sd[k] = __uint_as_float((unsigned)v);
            se[k] = (int)(v >> 32);
        }
        float asum = 0.f;
        #pragma unroll
        for (int k = 0; k < Kk; ++k) asum += sd[k];
        alpha = fmaf(alpha, 0.5f, asum);

        // ---- gather: u = 0.5u + sum d_k * WbT[e_k*1200 + cell0..+24)
        #pragma unroll
        for (int i = 0; i < 24; ++i) u[i] *= 0.5f;
        if (grp) {
            const float* wp = WbT + cell0;
            float4 buf[2][5][6];
            #pragma unroll
            for (int k = 0; k < 5; ++k) {
                const float* cp = wp + (size_t)se[k] * TOT;
                #pragma unroll
                for (int q = 0; q < 6; ++q)
                    buf[0][k][q] = *reinterpret_cast<const float4*>(cp + 4 * q);
            }
            #pragma unroll
            for (int b = 0; b < 5; ++b) {
                if (b < 4) {
                    #pragma unroll
                    for (int k = 0; k < 5; ++k) {
                        const float* cp = wp + (size_t)se[5 * (b + 1) + k] * TOT;
                        #pragma unroll
                        for (int q = 0; q < 6; ++q)
                            buf[(b + 1) & 1][k][q] =
                                *reinterpret_cast<const float4*>(cp + 4 * q);
                    }
                }
                #pragma unroll
                for (int k = 0; k < 5; ++k) {
                    float dk = sd[5 * b + k];
                    #pragma unroll
                    for (int q = 0; q < 6; ++q) {
                        float4 w = buf[b & 1][k][q];
                        u[4*q+0] = fmaf(dk, w.x, u[4*q+0]);
                        u[4*q+1] = fmaf(dk, w.y, u[4*q+1]);
                        u[4*q+2] = fmaf(dk, w.z, u[4*q+2]);
                        u[4*q+3] = fmaf(dk, w.w, u[4*q+3]);
                    }
                }
            }
        }

        // ---- chunk boundary: flush Y ring, stage next Za chunk
        if (tc == CH - 1) {
            const size_t t0 = (size_t)(t - (CH - 1)) * Kk;
            #pragma unroll
            for (int j = 0; j < 13; ++j) {
                int i = lane + j * 64;
                if (i < CH * Kk) YP[t0 + i] = ypk[i];
            }
            if (t + 1 < Tn) {
                const float* src = Za + (size_t)(t + 1) * Mg;
                #pragma unroll
                for (int j = 0; j < 25; ++j) {
                    int f = lane + j * 64;
                    *reinterpret_cast<float4*>(zs + 4 * f) =
                        *reinterpret_cast<const float4*>(src + 4 * f);
                }
            }
        }
    }

    // ---- epilogue: x_b, phi, psi
    if (grp) {
        float inv2 = (alpha == 0.f) ? 1.f : (1.f / alpha);
        #pragma unroll
        for (int i = 0; i < 24; ++i) {
            outTail[cell0 + i]           = ps[i] * inv2;
            outTail[TOT + cell0 + i]     = ps[i];
            outTail[2 * TOT + cell0 + i] = ps[i];
        }
    }
}

// ------------------------------------------------- preds = bd + sum val * WdT[idx]
__global__ void preds_k(const unsigned long long* __restrict__ YP,
                        const float* __restrict__ WdT, const float* __restrict__ bd,
                        float* __restrict__ out) {
    const int t = blockIdx.x;
    __shared__ float sv[Kk];
    __shared__ int   si[Kk];
    if (threadIdx.x < Kk) {
        unsigned long long v = YP[(size_t)t * Kk + threadIdx.x];
        sv[threadIdx.x] = __uint_as_float((unsigned)v);
        si[threadIdx.x] = (int)(v >> 32);
    }
    __syncthreads();
    for (int d = threadIdx.x; d < Din; d += 256) {
        float acc = bd[d];
        #pragma unroll
        for (int k = 0; k < Kk; ++k)
            acc = fmaf(sv[k], WdT[(size_t)si[k] * Din + d], acc);
        out[(size_t)t * Din + d] = acc;
    }
}

extern "C" void kernel_launch(void* const* d_in, const int* in_sizes, int n_in,
                              void* d_out, int out_size, void* d_ws, size_t ws_size,
                              hipStream_t stream) {
    const float* X  = (const float*)d_in[0];
    const float* Wa = (const float*)d_in[1];
    const float* ba = (const float*)d_in[2];
    const float* Wb = (const float*)d_in[3];
    const float* bb = (const float*)d_in[4];
    const float* Wd = (const float*)d_in[5];
    const float* bd = (const float*)d_in[6];
    float* out = (float*)d_out;

    float* w    = (float*)d_ws;
    float* Za   = w;                                    // 16384*200
    float* WbT  = Za  + (size_t)Tn * Mg;                // 1200*1200
    float* WdT  = WbT + (size_t)TOT * TOT;              // 200*784
    unsigned long long* YP =
        (unsigned long long*)(WdT + (size_t)Mg * Din);  // 16384*25 u64

    dim3 tb(32, 8);
    transpose_k<<<dim3((TOT + 31) / 32, (TOT + 31) / 32), tb, 0, stream>>>(Wb, WbT, TOT, TOT);
    transpose_k<<<dim3((Mg + 31) / 32, (Din + 31) / 32), tb, 0, stream>>>(Wd, WdT, Din, Mg);
    za_k<<<Tn / 16, 256, 0, stream>>>(X, Wa, ba, Za);
    serial_k<<<1, 64, 0, stream>>>(Za, WbT, bb, YP, out + (size_t)Tn * Din);
    preds_k<<<Tn, 256, 0, stream>>>(YP, WdT, bd, out);
}